// Round 7
// baseline (226.663 us; speedup 1.0000x reference)
//
#include <hip/hip_runtime.h>

#define B_  4
#define N_  4096
#define H_  16
#define BH_ 64
#define S_  16
#define ST_ 72          // f16 stride of k_out LDS tiles
#define EPS_ 1e-6f

// k_kvpart v8: per-WAVE private tiles [64 d][NST_ n] f16, single-buffered.
#define NST_ 40         // 80 B rows: 16B-aligned for b128 frag reads
#define WTILE_ (64 * NST_)          // one tensor tile, f16 elems
#define WPOOL_ (2 * WTILE_)         // K + V per wave

typedef _Float16 h2  __attribute__((ext_vector_type(2)));
typedef _Float16 h8  __attribute__((ext_vector_type(8)));
typedef float    f4v __attribute__((ext_vector_type(4)));

struct H2x2 { h2 a, b; };
struct H2x4 { h2 e[4]; };

__device__ __forceinline__ h8 ld_h8(const _Float16* p) {
    f4v r = *(const f4v*)p;                       // ds_read_b128
    return __builtin_bit_cast(h8, r);
}
__device__ __forceinline__ H2x4 ld_h2x4(const _Float16* p) {
    f4v r = *(const f4v*)p;
    return __builtin_bit_cast(H2x4, r);
}
__device__ __forceinline__ void st_h2x2(_Float16* p, h2 a, h2 b) {
    H2x2 t{a, b};
    *(float2*)p = __builtin_bit_cast(float2, t);  // ds_write_b64
}
__device__ __forceinline__ float phi(float x) {
    return x > 0.0f ? x + 1.0f : __expf(x);       // elu(x)+1
}
__device__ __forceinline__ float fdot2(h2 a, h2 b, float c) {
    return __builtin_amdgcn_fdot2(a, b, c, false);
}
// Pinned global load (cannot be sunk/recycled by the scheduler).
__device__ __forceinline__ f4v gload(const void* p) {
    f4v r;
    asm volatile("global_load_dwordx4 %0, %1, off"
                 : "=v"(r) : "v"(p) : "memory");
    return r;
}
#define VMW(N)                                                    \
    do {                                                          \
        asm volatile("s_waitcnt vmcnt(" #N ")" ::: "memory");     \
        __builtin_amdgcn_sched_barrier(0);                        \
    } while (0)

// ---------------------------------------------------------------------------
// Kernel 1a v8 — BARRIER-FREE. Theory: barrier lockstep made memory bursty
// (avg outstanding ~2 KB/CU -> 1.5 TB/s invariant to everything). Each wave
// is fully independent: wave = one (head h, n-slice s), owns a private
// 10 KB LDS tile pair, 8 chunks x 32 rows, per-wave vmcnt discipline only.
// grid (16 s, 4 h4, 4 b) x 256 thr; wave wv handles h = h4*4+wv (the 4 waves
// of a block read the same rows -> L2 locality preserved).
// ---------------------------------------------------------------------------
__global__ __launch_bounds__(256, 2) void k_kvpart(const float* __restrict__ K,
                                                   const float* __restrict__ V,
                                                   float* __restrict__ kvpart,
                                                   float* __restrict__ kspart) {
    const int s = blockIdx.x, h4 = blockIdx.y, b = blockIdx.z;
    const int t = threadIdx.x, wv = t >> 6, lane = t & 63;
    const int rp = lane >> 4, c4 = lane & 15;
    const int h = h4 * 4 + wv;

    __shared__ __align__(16) _Float16 pool[4 * WPOOL_];   // 40960 B

    _Float16* Kt = pool + wv * WPOOL_;
    _Float16* Vt = Kt + WTILE_;

    // payload: chunk = 32 rows; lane covers rows 8rp..8rp+7 at d = 4c4..+3
    f4v kr[8], vr[8];
    const float* baseK = K + ((size_t)(b * N_ + s * 256) * 1024 + h * 64 + c4 * 4);
    const float* baseV = V + ((size_t)(b * N_ + s * 256) * 1024 + h * 64 + c4 * 4);

    auto LOADX = [&](int chunk) {
        const int ro = (chunk * 32 + 8 * rp) * 1024;
        const float* gk = baseK + ro;
        const float* gv = baseV + ro;
#pragma unroll
        for (int r = 0; r < 8; ++r) kr[r] = gload(gk + r * 1024);
#pragma unroll
        for (int r = 0; r < 8; ++r) vr[r] = gload(gv + r * 1024);
    };
    auto STOREX = [&]() {
        const int nn = 8 * rp;
#pragma unroll
        for (int dj = 0; dj < 4; ++dj) {
            const int d = 4 * c4 + dj;
            h2 lo, hi;
            lo.x = (_Float16)phi(kr[0][dj]); lo.y = (_Float16)phi(kr[1][dj]);
            hi.x = (_Float16)phi(kr[2][dj]); hi.y = (_Float16)phi(kr[3][dj]);
            st_h2x2(&Kt[d * NST_ + nn], lo, hi);
            lo.x = (_Float16)phi(kr[4][dj]); lo.y = (_Float16)phi(kr[5][dj]);
            hi.x = (_Float16)phi(kr[6][dj]); hi.y = (_Float16)phi(kr[7][dj]);
            st_h2x2(&Kt[d * NST_ + nn + 4], lo, hi);
            lo.x = (_Float16)vr[0][dj]; lo.y = (_Float16)vr[1][dj];
            hi.x = (_Float16)vr[2][dj]; hi.y = (_Float16)vr[3][dj];
            st_h2x2(&Vt[d * NST_ + nn], lo, hi);
            lo.x = (_Float16)vr[4][dj]; lo.y = (_Float16)vr[5][dj];
            hi.x = (_Float16)vr[6][dj]; hi.y = (_Float16)vr[7][dj];
            st_h2x2(&Vt[d * NST_ + nn + 4], lo, hi);
        }
    };

    f4v acc[4][4];                    // [d-tile][m-tile], 64x64 output
#pragma unroll
    for (int i = 0; i < 4; ++i)
#pragma unroll
        for (int j = 0; j < 4; ++j) acc[i][j] = (f4v){0.f, 0.f, 0.f, 0.f};
    float ksum = 0.f;
    h2 one2; one2.x = (_Float16)1.0f; one2.y = (_Float16)1.0f;

    const int fo = rp * 8;            // k-offset within the 32-contraction

    auto COMPUTE = [&]() {
        h8 af[4], bf[4];
#pragma unroll
        for (int i = 0; i < 4; ++i) {
            af[i] = ld_h8(&Kt[(16 * i + c4) * NST_ + fo]);
            bf[i] = ld_h8(&Vt[(16 * i + c4) * NST_ + fo]);
        }
#pragma unroll
        for (int i = 0; i < 4; ++i)
#pragma unroll
            for (int j = 0; j < 4; ++j)
                acc[i][j] = __builtin_amdgcn_mfma_f32_16x16x32_f16(af[i], bf[j], acc[i][j], 0, 0, 0);
        // ksum: lane owns d = lane, sums its row over the chunk's 32 n
#pragma unroll
        for (int q = 0; q < 4; ++q) {
            H2x4 x = ld_h2x4(&Kt[lane * NST_ + q * 8]);
#pragma unroll
            for (int i = 0; i < 4; ++i) ksum = fdot2(x.e[i], one2, ksum);
        }
    };

    // per-wave pipeline, no block barriers: loads for c+1 fly under COMPUTE(c)
    LOADX(0);
    VMW(0);
    STOREX();
#pragma unroll
    for (int c = 0; c < 8; ++c) {
        if (c < 7) LOADX(c + 1);
        COMPUTE();
        if (c < 7) {
            VMW(0);       // chunk c+1 payload arrived (compute hid the latency)
            STOREX();     // compiler orders LDS read->write via lgkmcnt
        }
    }

    // epilogue (C layout: col=lane&15 -> m, row=(lane>>4)*4+r -> d; m89)
    const int bh = b * 16 + h;
    float* outp = kvpart + (size_t)(bh * S_ + s) * 4096;
#pragma unroll
    for (int i = 0; i < 4; ++i)
#pragma unroll
        for (int j = 0; j < 4; ++j)
#pragma unroll
            for (int r = 0; r < 4; ++r) {
                const int d = 16 * i + rp * 4 + r;
                const int m = 16 * j + c4;
                outp[d * 64 + m] = acc[i][j][r];
            }
    kspart[(size_t)(bh * S_ + s) * 64 + lane] = ksum;
}

// ---------------------------------------------------------------------------
// Kernel 1b: reduce partials -> KV, Ksum; Mt[j][d] = sum KV[d][m]*W[j][..].
// Unchanged from the passing v7.
// ---------------------------------------------------------------------------
__global__ __launch_bounds__(256, 2) void k_makeM(const float* __restrict__ kvpart,
                                                  const float* __restrict__ kspart,
                                                  const float* __restrict__ W,
                                                  _Float16* __restrict__ Mt,
                                                  float* __restrict__ Ksum) {
    const int bh = blockIdx.x, dq = blockIdx.y;
    const int h  = bh & 15;
    const int t  = threadIdx.x;

    __shared__ float KVs[16][68];
    __shared__ float Ws[64][68];

    const f4v* W4  = (const f4v*)W;

    f4v rr[S_];
    {
        const int row = t >> 4, c4 = t & 15;
        const float* g = kvpart + ((size_t)(bh * S_) * 4096 +
                                   (dq * 16 + row) * 64 + c4 * 4);
#pragma unroll
        for (int s = 0; s < S_; ++s) rr[s] = gload(g + (size_t)s * 4096);
    }
    for (int idx = t; idx < 1024; idx += 256) {
        int wrow = idx >> 4, wc = idx & 15;
        *(f4v*)&Ws[wrow][wc * 4] = W4[(size_t)wrow * 256 + h * 16 + wc];
    }
    if (dq == 0 && t < 64) {
        float ks = 0.f;
#pragma unroll
        for (int s = 0; s < S_; ++s) ks += kspart[(size_t)(bh * S_ + s) * 64 + t];
        Ksum[(size_t)bh * 64 + t] = ks;
    }
    VMW(0);
    {
        const int row = t >> 4, c4 = t & 15;
        f4v r = {0.f, 0.f, 0.f, 0.f};
#pragma unroll
        for (int s = 0; s < S_; ++s) r += rr[s];
        *(f4v*)&KVs[row][c4 * 4] = r;
    }
    __syncthreads();

    const int j = t >> 2, dl = (t & 3) * 4;
    float acc[4] = {0.f, 0.f, 0.f, 0.f};
#pragma unroll 4
    for (int m4 = 0; m4 < 16; ++m4) {
        f4v wr  = *(const f4v*)&Ws[j][m4 * 4];
        f4v kv0 = *(const f4v*)&KVs[dl + 0][m4 * 4];
        f4v kv1 = *(const f4v*)&KVs[dl + 1][m4 * 4];
        f4v kv2 = *(const f4v*)&KVs[dl + 2][m4 * 4];
        f4v kv3 = *(const f4v*)&KVs[dl + 3][m4 * 4];
        acc[0] += wr[0] * kv0[0] + wr[1] * kv0[1] + wr[2] * kv0[2] + wr[3] * kv0[3];
        acc[1] += wr[0] * kv1[0] + wr[1] * kv1[1] + wr[2] * kv1[2] + wr[3] * kv1[3];
        acc[2] += wr[0] * kv2[0] + wr[1] * kv2[1] + wr[2] * kv2[2] + wr[3] * kv2[3];
        acc[3] += wr[0] * kv3[0] + wr[1] * kv3[1] + wr[2] * kv3[2] + wr[3] * kv3[3];
    }
    h2 lo, hi;
    lo.x = (_Float16)acc[0]; lo.y = (_Float16)acc[1];
    hi.x = (_Float16)acc[2]; hi.y = (_Float16)acc[3];
    H2x2 pk{lo, hi};
    *(float2*)&Mt[((size_t)bh * 64 + j) * 64 + dq * 16 + dl] =
        __builtin_bit_cast(float2, pk);
}

// ---------------------------------------------------------------------------
// Kernel 2 v8: FUSED k_out + k_red. grid (64 nc, 4 b), 256 thr; loop over all
// 16 heads, facc accumulates, epilogue writes bias + sum directly to out.
// Eliminates the 16 MB outpart write + 16 MB read + k_red dispatch.
// Inner machinery identical to the passing v7.
// ---------------------------------------------------------------------------
__global__ __launch_bounds__(256, 2) void k_out(const float* __restrict__ Q,
                                                const _Float16* __restrict__ Mtg,
                                                const float* __restrict__ Ksum,
                                                const float* __restrict__ bout,
                                                float* __restrict__ out) {
    const int nc = blockIdx.x, b = blockIdx.y;
    const int n0 = nc * 64;
    const int t = threadIdx.x, w = t >> 6, lane = t & 63;
    const int rp4 = t >> 4, c4 = t & 15;

    __shared__ __align__(16) _Float16 pool[2 * 2 * 64 * ST_];
    __shared__ float zz[64];
    __shared__ h2 Kss[2][32];

    f4v qr[4], mr[2];
    float ksa = 0.f, ksb = 0.f;
    auto LOAD = [&](int hh) {
        const int bh = b * 16 + hh;
        const float* gq = Q + ((size_t)(b * N_ + n0 + rp4) * 1024 + hh * 64 + c4 * 4);
        qr[0] = gload(gq);
        qr[1] = gload(gq + 16 * 1024);
        qr[2] = gload(gq + 32 * 1024);
        qr[3] = gload(gq + 48 * 1024);
        const _Float16* gm = Mtg + ((size_t)bh * 4096 + t * 8);
        mr[0] = gload(gm);
        mr[1] = gload(gm + 2048);
        if (t < 32) {
            ksa = Ksum[(size_t)bh * 64 + 2 * t];
            ksb = Ksum[(size_t)bh * 64 + 2 * t + 1];
        }
    };
    auto STORE = [&](int buf) {
        _Float16* Qp = pool + buf * (2 * 64 * ST_);
        _Float16* Mt = Qp + 64 * ST_;
#pragma unroll
        for (int r = 0; r < 4; ++r) {
            int row = rp4 + 16 * r;
            h2 p0, p1;
            p0.x = (_Float16)phi(qr[r][0]); p0.y = (_Float16)phi(qr[r][1]);
            p1.x = (_Float16)phi(qr[r][2]); p1.y = (_Float16)phi(qr[r][3]);
            st_h2x2(&Qp[row * ST_ + 4 * c4], p0, p1);
        }
        *(f4v*)&Mt[(t >> 3) * ST_ + (t & 7) * 8] = mr[0];
        *(f4v*)&Mt[((t + 256) >> 3) * ST_ + (t & 7) * 8] = mr[1];
        if (t < 32) { h2 kk; kk.x = (_Float16)ksa; kk.y = (_Float16)ksb; Kss[buf][t] = kk; }
    };

    const int tn0 = 2 * (w >> 1), tj0 = 2 * (w & 1);
    const int rA = lane & 15, fo = (lane >> 4) * 8;
    float facc[2][2][4] = {{{0.f}}};

    LOAD(0);
    VMW(0);
    STORE(0);

    for (int hh = 0; hh < 16; ++hh) {
        if (hh + 1 < 16) LOAD(hh + 1);
        __syncthreads();
        const int buf = hh & 1;
        const _Float16* Qp = pool + buf * (2 * 64 * ST_);
        const _Float16* Mt = Qp + 64 * ST_;

        if (t < 64) {            // z-denominator for row t
            float zp = 0.f;
#pragma unroll
            for (int c = 0; c < 8; ++c) {
                H2x4 x = ld_h2x4(&Qp[t * ST_ + c * 8]);
#pragma unroll
                for (int i = 0; i < 4; ++i) zp = fdot2(x.e[i], Kss[buf][c * 4 + i], zp);
            }
            zz[t] = 1.0f / (zp + EPS_);
        }
        __syncthreads();

        f4v acc[2][2];
#pragma unroll
        for (int a = 0; a < 2; ++a)
#pragma unroll
            for (int bb = 0; bb < 2; ++bb) acc[a][bb] = (f4v){0.f, 0.f, 0.f, 0.f};
#pragma unroll
        for (int ks = 0; ks < 2; ++ks) {
            h8 a0 = ld_h8(&Qp[(16 * (tn0 + 0) + rA) * ST_ + ks * 32 + fo]);
            h8 a1 = ld_h8(&Qp[(16 * (tn0 + 1) + rA) * ST_ + ks * 32 + fo]);
            h8 b0 = ld_h8(&Mt[(16 * (tj0 + 0) + rA) * ST_ + ks * 32 + fo]);
            h8 b1 = ld_h8(&Mt[(16 * (tj0 + 1) + rA) * ST_ + ks * 32 + fo]);
            acc[0][0] = __builtin_amdgcn_mfma_f32_16x16x32_f16(a0, b0, acc[0][0], 0, 0, 0);
            acc[0][1] = __builtin_amdgcn_mfma_f32_16x16x32_f16(a0, b1, acc[0][1], 0, 0, 0);
            acc[1][0] = __builtin_amdgcn_mfma_f32_16x16x32_f16(a1, b0, acc[1][0], 0, 0, 0);
            acc[1][1] = __builtin_amdgcn_mfma_f32_16x16x32_f16(a1, b1, acc[1][1], 0, 0, 0);
        }
#pragma unroll
        for (int a = 0; a < 2; ++a)
#pragma unroll
            for (int r = 0; r < 4; ++r) {
                int row = 16 * (tn0 + a) + (lane >> 4) * 4 + r;
                float z = zz[row];
                facc[a][0][r] += z * acc[a][0][r];
                facc[a][1][r] += z * acc[a][1][r];
            }
        if (hh + 1 < 16) {
            VMW(0);
            STORE((hh + 1) & 1);
        }
    }

#pragma unroll
    for (int a = 0; a < 2; ++a)
#pragma unroll
        for (int bb = 0; bb < 2; ++bb) {
            const int j = 16 * (tj0 + bb) + (lane & 15);
            const float bj = bout[j];
#pragma unroll
            for (int r = 0; r < 4; ++r) {
                int n = 16 * (tn0 + a) + (lane >> 4) * 4 + r;
                out[(size_t)(b * N_ + n0 + n) * 64 + j] = bj + facc[a][bb][r];
            }
        }
}

// ---------------------------------------------------------------------------
extern "C" void kernel_launch(void* const* d_in, const int* in_sizes, int n_in,
                              void* d_out, int out_size, void* d_ws, size_t ws_size,
                              hipStream_t stream) {
    const float* q  = (const float*)d_in[0];
    const float* k  = (const float*)d_in[1];
    const float* v  = (const float*)d_in[2];
    const float* W  = (const float*)d_in[3];
    const float* bo = (const float*)d_in[4];
    float* out = (float*)d_out;

    float* ws      = (float*)d_ws;
    float* kvpart  = ws;                                    // 64*16*4096 = 16 MB
    float* kspart  = kvpart + (size_t)BH_ * S_ * 4096;      // 256 KB
    float* Mt      = kspart + (size_t)BH_ * S_ * 64;        // 64*4096 f16 = 512 KB
    float* Ksum    = Mt + (size_t)BH_ * 4096 / 2;           // 16 KB

    k_kvpart<<<dim3(S_, 4, 4), 256, 0, stream>>>(k, v, kvpart, kspart);
    k_makeM<<<dim3(BH_, 4), 256, 0, stream>>>(kvpart, kspart, W, (_Float16*)Mt, Ksum);
    k_out<<<dim3(N_ / 64, B_), 256, 0, stream>>>(q, (const _Float16*)Mt, Ksum, bo, out);
}

// Round 8
// 221.201 us; speedup vs baseline: 1.0247x; 1.0247x over previous
//
#include <hip/hip_runtime.h>

#define B_  4
#define N_  4096
#define H_  16
#define BH_ 64
#define S_  16
#define ST_ 72          // f16 stride of k_out LDS tiles
#define EPS_ 1e-6f

// k_kvpart: per-WAVE private tiles [64 d][NST_ n] f16, DOUBLE-buffered.
#define NST_ 40         // 80 B rows: 16B-aligned for b128 frag reads
#define WTILE_ (64 * NST_)          // one tensor tile, f16 elems (5120 B)
#define WPOOL_ (2 * WTILE_)         // K + V tile pair per buffer

typedef _Float16 h2  __attribute__((ext_vector_type(2)));
typedef _Float16 h8  __attribute__((ext_vector_type(8)));
typedef float    f4v __attribute__((ext_vector_type(4)));

struct H2x2 { h2 a, b; };
struct H2x4 { h2 e[4]; };

__device__ __forceinline__ h8 ld_h8(const _Float16* p) {
    f4v r = *(const f4v*)p;                       // ds_read_b128
    return __builtin_bit_cast(h8, r);
}
__device__ __forceinline__ H2x4 ld_h2x4(const _Float16* p) {
    f4v r = *(const f4v*)p;
    return __builtin_bit_cast(H2x4, r);
}
__device__ __forceinline__ void st_h2x2(_Float16* p, h2 a, h2 b) {
    H2x2 t{a, b};
    *(float2*)p = __builtin_bit_cast(float2, t);  // ds_write_b64
}
__device__ __forceinline__ float phi(float x) {
    return x > 0.0f ? x + 1.0f : __expf(x);       // elu(x)+1
}
__device__ __forceinline__ float fdot2(h2 a, h2 b, float c) {
    return __builtin_amdgcn_fdot2(a, b, c, false);
}
// Pinned global load (cannot be sunk/recycled by the scheduler).
__device__ __forceinline__ f4v gload(const void* p) {
    f4v r;
    asm volatile("global_load_dwordx4 %0, %1, off"
                 : "=v"(r) : "v"(p) : "memory");
    return r;
}
// Counted vmcnt wait. N>0 in the steady state — NEVER drain to 0 mid-loop
// (T4). v8's bug: VMW(0) per chunk drained the just-issued prefetch, turning
// the "pipeline" into burst/drain cycles (8 x ~7us = the invariant 60us).
#define VMW(N)                                                    \
    do {                                                          \
        asm volatile("s_waitcnt vmcnt(" #N ")" ::: "memory");     \
        __builtin_amdgcn_sched_barrier(0);                        \
    } while (0)
// LDS-op fence: waits pending ds_write/ds_read of this wave (WAR guard
// before re-issuing loads into the registers the ds_writes consumed).
#define LGKW()                                                    \
    do {                                                          \
        asm volatile("s_waitcnt lgkmcnt(0)" ::: "memory");        \
        __builtin_amdgcn_sched_barrier(0);                        \
    } while (0)

// Barrier without the vmcnt(0) drain __syncthreads() emits.
__device__ __forceinline__ void barrier_lgkm() {
    asm volatile("s_waitcnt lgkmcnt(0)" ::: "memory");
    __builtin_amdgcn_sched_barrier(0);
    __builtin_amdgcn_s_barrier();
}

// ---------------------------------------------------------------------------
// Kernel 1a v9 — barrier-free + COUNTED vmcnt (true T3/T4). Wave = one
// (head, s-slice), private double-buffered LDS tile pair, 8 chunks x 32 rows.
// Steady state: VMW(16) -> chunk c arrived while c+1's 16 loads stay in
// flight; STOREX(c); reissue 16 loads for c+2; COMPUTE(c). Outstanding
// never drops below 16 KB/wave -> continuous HBM stream.
// grid (16 s, 4 h4, 4 b) x 256 thr (4 waves; wave wv -> head h4*4+wv).
// ---------------------------------------------------------------------------
__global__ __launch_bounds__(256, 1) void k_kvpart(const float* __restrict__ K,
                                                   const float* __restrict__ V,
                                                   float* __restrict__ kvpart,
                                                   float* __restrict__ kspart) {
    const int s = blockIdx.x, h4 = blockIdx.y, b = blockIdx.z;
    const int t = threadIdx.x, wv = t >> 6, lane = t & 63;
    const int rp = lane >> 4, c4 = lane & 15;
    const int h = h4 * 4 + wv;

    __shared__ __align__(16) _Float16 pool[8 * WPOOL_];   // 81920 B

    // wave wv, buffer bf: tiles at pool + (wv*2+bf)*WPOOL_
    f4v kA[8], vA[8], kB[8], vB[8];
    const float* baseK = K + ((size_t)(b * N_ + s * 256) * 1024 + h * 64 + c4 * 4);
    const float* baseV = V + ((size_t)(b * N_ + s * 256) * 1024 + h * 64 + c4 * 4);

    auto LOADX = [&](f4v* kr, f4v* vr, int chunk) {
        const int ro = (chunk * 32 + 8 * rp) * 1024;
        const float* gk = baseK + ro;
        const float* gv = baseV + ro;
#pragma unroll
        for (int r = 0; r < 8; ++r) kr[r] = gload(gk + r * 1024);
#pragma unroll
        for (int r = 0; r < 8; ++r) vr[r] = gload(gv + r * 1024);
    };
    auto STOREX = [&](const f4v* kr, const f4v* vr, int bf) {
        _Float16* Kt = pool + (wv * 2 + bf) * WPOOL_;
        _Float16* Vt = Kt + WTILE_;
        const int nn = 8 * rp;
#pragma unroll
        for (int dj = 0; dj < 4; ++dj) {
            const int d = 4 * c4 + dj;
            h2 lo, hi;
            lo.x = (_Float16)phi(kr[0][dj]); lo.y = (_Float16)phi(kr[1][dj]);
            hi.x = (_Float16)phi(kr[2][dj]); hi.y = (_Float16)phi(kr[3][dj]);
            st_h2x2(&Kt[d * NST_ + nn], lo, hi);
            lo.x = (_Float16)phi(kr[4][dj]); lo.y = (_Float16)phi(kr[5][dj]);
            hi.x = (_Float16)phi(kr[6][dj]); hi.y = (_Float16)phi(kr[7][dj]);
            st_h2x2(&Kt[d * NST_ + nn + 4], lo, hi);
            lo.x = (_Float16)vr[0][dj]; lo.y = (_Float16)vr[1][dj];
            hi.x = (_Float16)vr[2][dj]; hi.y = (_Float16)vr[3][dj];
            st_h2x2(&Vt[d * NST_ + nn], lo, hi);
            lo.x = (_Float16)vr[4][dj]; lo.y = (_Float16)vr[5][dj];
            hi.x = (_Float16)vr[6][dj]; hi.y = (_Float16)vr[7][dj];
            st_h2x2(&Vt[d * NST_ + nn + 4], lo, hi);
        }
    };

    f4v acc[4][4];                    // [d-tile][m-tile], 64x64 output
#pragma unroll
    for (int i = 0; i < 4; ++i)
#pragma unroll
        for (int j = 0; j < 4; ++j) acc[i][j] = (f4v){0.f, 0.f, 0.f, 0.f};
    float ksum = 0.f;
    h2 one2; one2.x = (_Float16)1.0f; one2.y = (_Float16)1.0f;

    const int fo = rp * 8;            // k-offset within the 32-contraction

    auto COMPUTE = [&](int bf) {
        const _Float16* Kt = pool + (wv * 2 + bf) * WPOOL_;
        const _Float16* Vt = Kt + WTILE_;
        h8 af[4], bfv[4];
#pragma unroll
        for (int i = 0; i < 4; ++i) {
            af[i]  = ld_h8(&Kt[(16 * i + c4) * NST_ + fo]);
            bfv[i] = ld_h8(&Vt[(16 * i + c4) * NST_ + fo]);
        }
#pragma unroll
        for (int i = 0; i < 4; ++i)
#pragma unroll
            for (int j = 0; j < 4; ++j)
                acc[i][j] = __builtin_amdgcn_mfma_f32_16x16x32_f16(af[i], bfv[j], acc[i][j], 0, 0, 0);
        // ksum: lane owns d = lane, sums its row over the chunk's 32 n
#pragma unroll
        for (int q = 0; q < 4; ++q) {
            H2x4 x = ld_h2x4(&Kt[lane * NST_ + q * 8]);
#pragma unroll
            for (int i = 0; i < 4; ++i) ksum = fdot2(x.e[i], one2, ksum);
        }
    };

    // 2-deep pipeline, counted vmcnt; LGKW before each reg-set reuse (WAR).
    LOADX(kA, vA, 0);
    LOADX(kB, vB, 1);
    VMW(16); STOREX(kA, vA, 0); LGKW(); LOADX(kA, vA, 2); COMPUTE(0);  // c0
    VMW(16); STOREX(kB, vB, 1); LGKW(); LOADX(kB, vB, 3); COMPUTE(1);  // c1
    VMW(16); STOREX(kA, vA, 0); LGKW(); LOADX(kA, vA, 4); COMPUTE(0);  // c2
    VMW(16); STOREX(kB, vB, 1); LGKW(); LOADX(kB, vB, 5); COMPUTE(1);  // c3
    VMW(16); STOREX(kA, vA, 0); LGKW(); LOADX(kA, vA, 6); COMPUTE(0);  // c4
    VMW(16); STOREX(kB, vB, 1); LGKW(); LOADX(kB, vB, 7); COMPUTE(1);  // c5
    VMW(16); STOREX(kA, vA, 0); COMPUTE(0);                            // c6
    VMW(0);  STOREX(kB, vB, 1); COMPUTE(1);                            // c7

    // epilogue (C layout: col=lane&15 -> m, row=(lane>>4)*4+r -> d; m89)
    const int bh = b * 16 + h;
    float* outp = kvpart + (size_t)(bh * S_ + s) * 4096;
#pragma unroll
    for (int i = 0; i < 4; ++i)
#pragma unroll
        for (int j = 0; j < 4; ++j)
#pragma unroll
            for (int r = 0; r < 4; ++r) {
                const int d = 16 * i + rp * 4 + r;
                const int m = 16 * j + c4;
                outp[d * 64 + m] = acc[i][j][r];
            }
    kspart[(size_t)(bh * S_ + s) * 64 + lane] = ksum;
}

// ---------------------------------------------------------------------------
// Kernel 1b: reduce partials -> KV, Ksum; Mt[j][d] = sum KV[d][m]*W[j][..].
// Unchanged (passing).
// ---------------------------------------------------------------------------
__global__ __launch_bounds__(256, 2) void k_makeM(const float* __restrict__ kvpart,
                                                  const float* __restrict__ kspart,
                                                  const float* __restrict__ W,
                                                  _Float16* __restrict__ Mt,
                                                  float* __restrict__ Ksum) {
    const int bh = blockIdx.x, dq = blockIdx.y;
    const int h  = bh & 15;
    const int t  = threadIdx.x;

    __shared__ float KVs[16][68];
    __shared__ float Ws[64][68];

    const f4v* W4  = (const f4v*)W;

    f4v rr[S_];
    {
        const int row = t >> 4, c4 = t & 15;
        const float* g = kvpart + ((size_t)(bh * S_) * 4096 +
                                   (dq * 16 + row) * 64 + c4 * 4);
#pragma unroll
        for (int s = 0; s < S_; ++s) rr[s] = gload(g + (size_t)s * 4096);
    }
    for (int idx = t; idx < 1024; idx += 256) {
        int wrow = idx >> 4, wc = idx & 15;
        *(f4v*)&Ws[wrow][wc * 4] = W4[(size_t)wrow * 256 + h * 16 + wc];
    }
    if (dq == 0 && t < 64) {
        float ks = 0.f;
#pragma unroll
        for (int s = 0; s < S_; ++s) ks += kspart[(size_t)(bh * S_ + s) * 64 + t];
        Ksum[(size_t)bh * 64 + t] = ks;
    }
    VMW(0);
    {
        const int row = t >> 4, c4 = t & 15;
        f4v r = {0.f, 0.f, 0.f, 0.f};
#pragma unroll
        for (int s = 0; s < S_; ++s) r += rr[s];
        *(f4v*)&KVs[row][c4 * 4] = r;
    }
    __syncthreads();

    const int j = t >> 2, dl = (t & 3) * 4;
    float acc[4] = {0.f, 0.f, 0.f, 0.f};
#pragma unroll 4
    for (int m4 = 0; m4 < 16; ++m4) {
        f4v wr  = *(const f4v*)&Ws[j][m4 * 4];
        f4v kv0 = *(const f4v*)&KVs[dl + 0][m4 * 4];
        f4v kv1 = *(const f4v*)&KVs[dl + 1][m4 * 4];
        f4v kv2 = *(const f4v*)&KVs[dl + 2][m4 * 4];
        f4v kv3 = *(const f4v*)&KVs[dl + 3][m4 * 4];
        acc[0] += wr[0] * kv0[0] + wr[1] * kv0[1] + wr[2] * kv0[2] + wr[3] * kv0[3];
        acc[1] += wr[0] * kv1[0] + wr[1] * kv1[1] + wr[2] * kv1[2] + wr[3] * kv1[3];
        acc[2] += wr[0] * kv2[0] + wr[1] * kv2[1] + wr[2] * kv2[2] + wr[3] * kv2[3];
        acc[3] += wr[0] * kv3[0] + wr[1] * kv3[1] + wr[2] * kv3[2] + wr[3] * kv3[3];
    }
    h2 lo, hi;
    lo.x = (_Float16)acc[0]; lo.y = (_Float16)acc[1];
    hi.x = (_Float16)acc[2]; hi.y = (_Float16)acc[3];
    H2x2 pk{lo, hi};
    *(float2*)&Mt[((size_t)bh * 64 + j) * 64 + dq * 16 + dl] =
        __builtin_bit_cast(float2, pk);
}

// ---------------------------------------------------------------------------
// Kernel 2 v9: fused k_out+k_red (16 heads/block) with NON-draining barriers:
// v8 used __syncthreads() right after issuing the next head's loads — its
// implicit vmcnt(0) drained them on the spot. barrier_lgkm keeps them in
// flight; VMW(0) only at the consumption point (after z-phase + MFMA).
// ---------------------------------------------------------------------------
__global__ __launch_bounds__(256, 2) void k_out(const float* __restrict__ Q,
                                                const _Float16* __restrict__ Mtg,
                                                const float* __restrict__ Ksum,
                                                const float* __restrict__ bout,
                                                float* __restrict__ out) {
    const int nc = blockIdx.x, b = blockIdx.y;
    const int n0 = nc * 64;
    const int t = threadIdx.x, w = t >> 6, lane = t & 63;
    const int rp4 = t >> 4, c4 = t & 15;

    __shared__ __align__(16) _Float16 pool[2 * 2 * 64 * ST_];
    __shared__ float zz[64];
    __shared__ h2 Kss[2][32];

    f4v qr[4], mr[2];
    float ksa = 0.f, ksb = 0.f;
    auto LOAD = [&](int hh) {
        const int bh = b * 16 + hh;
        const float* gq = Q + ((size_t)(b * N_ + n0 + rp4) * 1024 + hh * 64 + c4 * 4);
        qr[0] = gload(gq);
        qr[1] = gload(gq + 16 * 1024);
        qr[2] = gload(gq + 32 * 1024);
        qr[3] = gload(gq + 48 * 1024);
        const _Float16* gm = Mtg + ((size_t)bh * 4096 + t * 8);
        mr[0] = gload(gm);
        mr[1] = gload(gm + 2048);
        if (t < 32) {
            ksa = Ksum[(size_t)bh * 64 + 2 * t];
            ksb = Ksum[(size_t)bh * 64 + 2 * t + 1];
        }
    };
    auto STORE = [&](int buf) {
        _Float16* Qp = pool + buf * (2 * 64 * ST_);
        _Float16* Mt = Qp + 64 * ST_;
#pragma unroll
        for (int r = 0; r < 4; ++r) {
            int row = rp4 + 16 * r;
            h2 p0, p1;
            p0.x = (_Float16)phi(qr[r][0]); p0.y = (_Float16)phi(qr[r][1]);
            p1.x = (_Float16)phi(qr[r][2]); p1.y = (_Float16)phi(qr[r][3]);
            st_h2x2(&Qp[row * ST_ + 4 * c4], p0, p1);
        }
        *(f4v*)&Mt[(t >> 3) * ST_ + (t & 7) * 8] = mr[0];
        *(f4v*)&Mt[((t + 256) >> 3) * ST_ + (t & 7) * 8] = mr[1];
        if (t < 32) { h2 kk; kk.x = (_Float16)ksa; kk.y = (_Float16)ksb; Kss[buf][t] = kk; }
    };

    const int tn0 = 2 * (w >> 1), tj0 = 2 * (w & 1);
    const int rA = lane & 15, fo = (lane >> 4) * 8;
    float facc[2][2][4] = {{{0.f}}};

    LOAD(0);
    VMW(0);
    STORE(0);

    for (int hh = 0; hh < 16; ++hh) {
        if (hh + 1 < 16) { LGKW(); LOAD(hh + 1); }
        barrier_lgkm();
        const int buf = hh & 1;
        const _Float16* Qp = pool + buf * (2 * 64 * ST_);
        const _Float16* Mt = Qp + 64 * ST_;

        if (t < 64) {            // z-denominator for row t
            float zp = 0.f;
#pragma unroll
            for (int c = 0; c < 8; ++c) {
                H2x4 x = ld_h2x4(&Qp[t * ST_ + c * 8]);
#pragma unroll
                for (int i = 0; i < 4; ++i) zp = fdot2(x.e[i], Kss[buf][c * 4 + i], zp);
            }
            zz[t] = 1.0f / (zp + EPS_);
        }
        barrier_lgkm();

        f4v acc[2][2];
#pragma unroll
        for (int a = 0; a < 2; ++a)
#pragma unroll
            for (int bb = 0; bb < 2; ++bb) acc[a][bb] = (f4v){0.f, 0.f, 0.f, 0.f};
#pragma unroll
        for (int ks = 0; ks < 2; ++ks) {
            h8 a0 = ld_h8(&Qp[(16 * (tn0 + 0) + rA) * ST_ + ks * 32 + fo]);
            h8 a1 = ld_h8(&Qp[(16 * (tn0 + 1) + rA) * ST_ + ks * 32 + fo]);
            h8 b0 = ld_h8(&Mt[(16 * (tj0 + 0) + rA) * ST_ + ks * 32 + fo]);
            h8 b1 = ld_h8(&Mt[(16 * (tj0 + 1) + rA) * ST_ + ks * 32 + fo]);
            acc[0][0] = __builtin_amdgcn_mfma_f32_16x16x32_f16(a0, b0, acc[0][0], 0, 0, 0);
            acc[0][1] = __builtin_amdgcn_mfma_f32_16x16x32_f16(a0, b1, acc[0][1], 0, 0, 0);
            acc[1][0] = __builtin_amdgcn_mfma_f32_16x16x32_f16(a1, b0, acc[1][0], 0, 0, 0);
            acc[1][1] = __builtin_amdgcn_mfma_f32_16x16x32_f16(a1, b1, acc[1][1], 0, 0, 0);
        }
#pragma unroll
        for (int a = 0; a < 2; ++a)
#pragma unroll
            for (int r = 0; r < 4; ++r) {
                int row = 16 * (tn0 + a) + (lane >> 4) * 4 + r;
                float z = zz[row];
                facc[a][0][r] += z * acc[a][0][r];
                facc[a][1][r] += z * acc[a][1][r];
            }
        if (hh + 1 < 16) {
            VMW(0);
            STORE((hh + 1) & 1);
        }
    }

#pragma unroll
    for (int a = 0; a < 2; ++a)
#pragma unroll
        for (int bb = 0; bb < 2; ++bb) {
            const int j = 16 * (tj0 + bb) + (lane & 15);
            const float bj = bout[j];
#pragma unroll
            for (int r = 0; r < 4; ++r) {
                int n = 16 * (tn0 + a) + (lane >> 4) * 4 + r;
                out[(size_t)(b * N_ + n0 + n) * 64 + j] = bj + facc[a][bb][r];
            }
        }
}

// ---------------------------------------------------------------------------
extern "C" void kernel_launch(void* const* d_in, const int* in_sizes, int n_in,
                              void* d_out, int out_size, void* d_ws, size_t ws_size,
                              hipStream_t stream) {
    const float* q  = (const float*)d_in[0];
    const float* k  = (const float*)d_in[1];
    const float* v  = (const float*)d_in[2];
    const float* W  = (const float*)d_in[3];
    const float* bo = (const float*)d_in[4];
    float* out = (float*)d_out;

    float* ws      = (float*)d_ws;
    float* kvpart  = ws;                                    // 64*16*4096 = 16 MB
    float* kspart  = kvpart + (size_t)BH_ * S_ * 4096;      // 256 KB
    float* Mt      = kspart + (size_t)BH_ * S_ * 64;        // 64*4096 f16 = 512 KB
    float* Ksum    = Mt + (size_t)BH_ * 4096 / 2;           // 16 KB

    k_kvpart<<<dim3(S_, 4, 4), 256, 0, stream>>>(k, v, kvpart, kspart);
    k_makeM<<<dim3(BH_, 4), 256, 0, stream>>>(kvpart, kspart, W, (_Float16*)Mt, Ksum);
    k_out<<<dim3(N_ / 64, B_), 256, 0, stream>>>(q, (const _Float16*)Mt, Ksum, bo, out);
}